// Round 1
// baseline (1229.244 us; speedup 1.0000x reference)
//
#include <hip/hip_runtime.h>

typedef __attribute__((ext_vector_type(8))) short short8v;
typedef __attribute__((ext_vector_type(8))) unsigned short ushort8v;
typedef __attribute__((ext_vector_type(4))) float f32x4;

__device__ __forceinline__ unsigned short f2b(float f) {
  unsigned int u = __float_as_uint(f);
  unsigned int r = (u + 0x7FFFu + ((u >> 16) & 1u)) >> 16;
  return (unsigned short)r;
}
__device__ __forceinline__ float b2f(unsigned short h) {
  return __uint_as_float(((unsigned int)h) << 16);
}
__device__ __forceinline__ float gelu_f(float x) {
  float z = 0.7978845608028654f * (x + 0.044715f * x * x * x);
  float e = __expf(2.0f * z);
  float t = 1.0f - 2.0f / (e + 1.0f);   // tanh(z), stable at +/-inf
  return 0.5f * x * (1.0f + t);
}

// ---------------- transpose + f32->bf16 convert: w[K][N] -> wt[N][K] ----------------
__global__ __launch_bounds__(256) void k_transpose_cvt(const float* __restrict__ w,
                                                       unsigned short* __restrict__ wt,
                                                       int K, int N) {
  __shared__ float tile[64][65];
  int tn = blockIdx.x * 64, tk = blockIdx.y * 64;
  int c = threadIdx.x & 63, r0 = threadIdx.x >> 6;
#pragma unroll
  for (int p = 0; p < 16; ++p) {
    int r = r0 + p * 4;
    tile[r][c] = w[(size_t)(tk + r) * N + tn + c];
  }
  __syncthreads();
#pragma unroll
  for (int p = 0; p < 16; ++p) {
    int r = r0 + p * 4;
    wt[(size_t)(tn + r) * K + tk + c] = f2b(tile[c][r]);
  }
}

// ---------------- elementwise f32 -> bf16 ----------------
__global__ void k_cvt_bf16(const float* __restrict__ in, unsigned short* __restrict__ out, int n) {
  int i = blockIdx.x * 256 + threadIdx.x;
  if (i < n) out[i] = f2b(in[i]);
}

// ---------------- LayerNorm over C=1024, out bf16 ----------------
__global__ __launch_bounds__(256) void k_ln(const float* __restrict__ in,
                                            const float* __restrict__ g,
                                            const float* __restrict__ b,
                                            unsigned short* __restrict__ out) {
  int row = blockIdx.x;
  const float* x = in + (size_t)row * 1024;
  int t = threadIdx.x;
  float v0 = x[t], v1 = x[t + 256], v2 = x[t + 512], v3 = x[t + 768];
  float s = v0 + v1 + v2 + v3;
  float s2 = v0 * v0 + v1 * v1 + v2 * v2 + v3 * v3;
#pragma unroll
  for (int m = 1; m < 64; m <<= 1) { s += __shfl_xor(s, m); s2 += __shfl_xor(s2, m); }
  __shared__ float rs[4], rs2[4];
  int w = t >> 6;
  if ((t & 63) == 0) { rs[w] = s; rs2[w] = s2; }
  __syncthreads();
  s = rs[0] + rs[1] + rs[2] + rs[3];
  s2 = rs2[0] + rs2[1] + rs2[2] + rs2[3];
  float mean = s * (1.0f / 1024.0f);
  float var = s2 * (1.0f / 1024.0f) - mean * mean;
  float rinv = rsqrtf(var + 1e-5f);
  unsigned short* o = out + (size_t)row * 1024;
  o[t]       = f2b((v0 - mean) * rinv * g[t]       + b[t]);
  o[t + 256] = f2b((v1 - mean) * rinv * g[t + 256] + b[t + 256]);
  o[t + 512] = f2b((v2 - mean) * rinv * g[t + 512] + b[t + 512]);
  o[t + 768] = f2b((v3 - mean) * rinv * g[t + 768] + b[t + 768]);
}

// ---------------- GEMM: out[M][N] = A[M][K](bf16) @ W[N][K](bf16)^T + bias (+gelu)(+res) ----
template <bool GELU, bool WF32, bool WBF16, int NRES>
__global__ __launch_bounds__(256) void k_gemm(const unsigned short* __restrict__ A,
                                              const unsigned short* __restrict__ W,
                                              const float* __restrict__ bias,
                                              const float* __restrict__ res1,
                                              const float* __restrict__ res2,
                                              float* __restrict__ outF,
                                              unsigned short* __restrict__ outB,
                                              int M, int N, int K) {
  __shared__ unsigned short lA[128 * 32];
  __shared__ unsigned short lB[128 * 32];
  int t = threadIdx.x;
  int tile_n = blockIdx.x * 128, tile_m = blockIdx.y * 128;
  int lane = t & 63, w = t >> 6;
  int wm = (w >> 1) * 64, wn = (w & 1) * 64;
  int lr = lane & 15;
  int kh = (lane >> 4) * 8;
  f32x4 acc[4][4];
#pragma unroll
  for (int i = 0; i < 4; ++i)
#pragma unroll
    for (int j = 0; j < 4; ++j) acc[i][j] = f32x4{0.f, 0.f, 0.f, 0.f};

  for (int kt = 0; kt < K; kt += 32) {
    __syncthreads();
#pragma unroll
    for (int r = 0; r < 2; ++r) {
      int e = r * 2048 + t * 8;
      int row = e >> 5, c = e & 31;
      int gr = tile_m + row; gr = gr < M ? gr : M - 1;
      *(ushort8v*)&lA[e] = *(const ushort8v*)&A[(size_t)gr * K + kt + c];
      *(ushort8v*)&lB[e] = *(const ushort8v*)&W[(size_t)(tile_n + row) * K + kt + c];
    }
    __syncthreads();
    short8v af[4], bfr[4];
#pragma unroll
    for (int i = 0; i < 4; ++i) af[i] = *(const short8v*)&lA[(wm + i * 16 + lr) * 32 + kh];
#pragma unroll
    for (int i = 0; i < 4; ++i) bfr[i] = *(const short8v*)&lB[(wn + i * 16 + lr) * 32 + kh];
#pragma unroll
    for (int i = 0; i < 4; ++i)
#pragma unroll
      for (int j = 0; j < 4; ++j)
        acc[i][j] = __builtin_amdgcn_mfma_f32_16x16x32_bf16(af[i], bfr[j], acc[i][j], 0, 0, 0);
  }
  int r0 = (lane >> 4) * 4;
#pragma unroll
  for (int i = 0; i < 4; ++i) {
#pragma unroll
    for (int j = 0; j < 4; ++j) {
      int col = tile_n + wn + j * 16 + lr;
      float bv = bias[col];
#pragma unroll
      for (int q = 0; q < 4; ++q) {
        int row = tile_m + wm + i * 16 + r0 + q;
        if (row < M) {
          float v = acc[i][j][q] + bv;
          if (GELU) v = gelu_f(v);
          size_t o = (size_t)row * N + col;
          if (NRES >= 1) v += res1[o];
          if (NRES >= 2) v += res2[o];
          if (WF32) outF[o] = v;
          if (WBF16) outB[o] = f2b(v);
        }
      }
    }
  }
}

// ---------------- self-attention (causal), scalar online-softmax flash ----------------
// qkv: [B*T][3072] bf16 (q|k|v each 1024, head h at h*64). out: [B*T][1024] bf16.
__global__ __launch_bounds__(256) void k_self_attn(const unsigned short* __restrict__ qkv,
                                                   unsigned short* __restrict__ out) {
  __shared__ float Kl[64][68];
  __shared__ float Vl[64][68];
  int qb = blockIdx.x;  // 16 query blocks
  int bh = blockIdx.y;  // 64 (b,h)
  int b = bh >> 4, h = bh & 15;
  int t = threadIdx.x;
  int g = t >> 2, p = t & 3;
  int qi = qb * 64 + g;
  size_t qrow = ((size_t)b * 1024 + qi) * 3072 + h * 64;
  float q[64];
#pragma unroll
  for (int d = 0; d < 64; ++d) q[d] = b2f(qkv[qrow + d]);
  float m = -__builtin_inff(), l = 0.0f;
  float acc[64];
#pragma unroll
  for (int d = 0; d < 64; ++d) acc[d] = 0.0f;

  for (int kt = 0; kt <= qb; ++kt) {
    __syncthreads();
    for (int idx = t; idx < 4096; idx += 256) {
      int k = idx >> 6, d = idx & 63;
      size_t krow = ((size_t)b * 1024 + kt * 64 + k) * 3072 + h * 64;
      Kl[k][d] = b2f(qkv[krow + 1024 + d]);
      Vl[k][d] = b2f(qkv[krow + 2048 + d]);
    }
    __syncthreads();
    int kmax = (kt == qb) ? (g + 1) : 64;
    for (int kk = p; kk < kmax; kk += 4) {
      float s = 0.0f;
#pragma unroll
      for (int d4 = 0; d4 < 16; ++d4) {
        const f32x4 kv4 = *(const f32x4*)&Kl[kk][d4 * 4];
        s += q[d4 * 4 + 0] * kv4[0] + q[d4 * 4 + 1] * kv4[1] +
             q[d4 * 4 + 2] * kv4[2] + q[d4 * 4 + 3] * kv4[3];
      }
      s *= 0.125f;
      float mn = fmaxf(m, s);
      float f = __expf(m - mn);
      float pp = __expf(s - mn);
      l = l * f + pp;
#pragma unroll
      for (int d4 = 0; d4 < 16; ++d4) {
        const f32x4 vv = *(const f32x4*)&Vl[kk][d4 * 4];
#pragma unroll
        for (int u = 0; u < 4; ++u) acc[d4 * 4 + u] = acc[d4 * 4 + u] * f + pp * vv[u];
      }
      m = mn;
    }
  }
  float mA = fmaxf(m, __shfl_xor(m, 1));
  mA = fmaxf(mA, __shfl_xor(mA, 2));
  float f = __expf(m - mA);
  l *= f;
  l += __shfl_xor(l, 1);
  l += __shfl_xor(l, 2);
#pragma unroll
  for (int d = 0; d < 64; ++d) {
    float a = acc[d] * f;
    a += __shfl_xor(a, 1);
    a += __shfl_xor(a, 2);
    acc[d] = a;
  }
  if (p == 0) {
    float inv = 1.0f / l;
    size_t orow = ((size_t)b * 1024 + qi) * 1024 + h * 64;
#pragma unroll
    for (int d = 0; d < 64; ++d) out[orow + d] = f2b(acc[d] * inv);
  }
}

// ---------------- cross-attention (no mask, Tk=257) ----------------
// q2: [B*T][1024] bf16. kv: [B*257][2048] bf16 (k|v each 1024). out: [B*T][1024] bf16.
__global__ __launch_bounds__(256) void k_cross_attn(const unsigned short* __restrict__ q2,
                                                    const unsigned short* __restrict__ kv,
                                                    unsigned short* __restrict__ out) {
  __shared__ float Kl[64][68];
  __shared__ float Vl[64][68];
  int qb = blockIdx.x;
  int bh = blockIdx.y;
  int b = bh >> 4, h = bh & 15;
  int t = threadIdx.x;
  int g = t >> 2, p = t & 3;
  int qi = qb * 64 + g;
  size_t qrow = ((size_t)b * 1024 + qi) * 1024 + h * 64;
  float q[64];
#pragma unroll
  for (int d = 0; d < 64; ++d) q[d] = b2f(q2[qrow + d]);
  float m = -__builtin_inff(), l = 0.0f;
  float acc[64];
#pragma unroll
  for (int d = 0; d < 64; ++d) acc[d] = 0.0f;

  for (int kt = 0; kt < 5; ++kt) {
    __syncthreads();
    for (int idx = t; idx < 4096; idx += 256) {
      int k = idx >> 6, d = idx & 63;
      int kg = kt * 64 + k;
      if (kg < 257) {
        size_t krow = ((size_t)b * 257 + kg) * 2048 + h * 64;
        Kl[k][d] = b2f(kv[krow + d]);
        Vl[k][d] = b2f(kv[krow + 1024 + d]);
      }
    }
    __syncthreads();
    int kmax = 257 - kt * 64; if (kmax > 64) kmax = 64;
    for (int kk = p; kk < kmax; kk += 4) {
      float s = 0.0f;
#pragma unroll
      for (int d4 = 0; d4 < 16; ++d4) {
        const f32x4 kv4 = *(const f32x4*)&Kl[kk][d4 * 4];
        s += q[d4 * 4 + 0] * kv4[0] + q[d4 * 4 + 1] * kv4[1] +
             q[d4 * 4 + 2] * kv4[2] + q[d4 * 4 + 3] * kv4[3];
      }
      s *= 0.125f;
      float mn = fmaxf(m, s);
      float f = __expf(m - mn);
      float pp = __expf(s - mn);
      l = l * f + pp;
#pragma unroll
      for (int d4 = 0; d4 < 16; ++d4) {
        const f32x4 vv = *(const f32x4*)&Vl[kk][d4 * 4];
#pragma unroll
        for (int u = 0; u < 4; ++u) acc[d4 * 4 + u] = acc[d4 * 4 + u] * f + pp * vv[u];
      }
      m = mn;
    }
  }
  float mA = fmaxf(m, __shfl_xor(m, 1));
  mA = fmaxf(mA, __shfl_xor(mA, 2));
  float f = __expf(m - mA);
  l *= f;
  l += __shfl_xor(l, 1);
  l += __shfl_xor(l, 2);
#pragma unroll
  for (int d = 0; d < 64; ++d) {
    float a = acc[d] * f;
    a += __shfl_xor(a, 1);
    a += __shfl_xor(a, 2);
    acc[d] = a;
  }
  if (p == 0) {
    float inv = 1.0f / l;
    size_t orow = ((size_t)b * 1024 + qi) * 1024 + h * 64;
#pragma unroll
    for (int d = 0; d < 64; ++d) out[orow + d] = f2b(acc[d] * inv);
  }
}

extern "C" void kernel_launch(void* const* d_in, const int* in_sizes, int n_in,
                              void* d_out, int out_size, void* d_ws, size_t ws_size,
                              hipStream_t stream) {
  (void)in_sizes; (void)n_in; (void)out_size; (void)ws_size;
  const float* x       = (const float*)d_in[0];
  const float* enc     = (const float*)d_in[1];
  const float* ln1_g   = (const float*)d_in[3];
  const float* ln1_b   = (const float*)d_in[4];
  const float* ln2_g   = (const float*)d_in[5];
  const float* ln2_b   = (const float*)d_in[6];
  const float* ln3_g   = (const float*)d_in[7];
  const float* ln3_b   = (const float*)d_in[8];
  const float* attn_w  = (const float*)d_in[9];
  const float* attn_b  = (const float*)d_in[10];
  const float* aproj_w = (const float*)d_in[11];
  const float* aproj_b = (const float*)d_in[12];
  const float* ca_w    = (const float*)d_in[13];
  const float* ca_b    = (const float*)d_in[14];
  const float* caproj_w= (const float*)d_in[15];
  const float* caproj_b= (const float*)d_in[16];
  const float* fc_w    = (const float*)d_in[17];
  const float* fc_b    = (const float*)d_in[18];
  const float* mproj_w = (const float*)d_in[19];
  const float* mproj_b = (const float*)d_in[20];
  const float* down_w  = (const float*)d_in[21];
  const float* down_b  = (const float*)d_in[22];
  const float* up_w    = (const float*)d_in[23];
  const float* up_b    = (const float*)d_in[24];
  float* out = (float*)d_out;
  char* ws = (char*)d_ws;

  const size_t O_WATTN = 0, O_WAPROJ = 6291456, O_WCA = 8388608, O_WCAPROJ = 14680064,
               O_WFC = 16777216, O_WMPROJ = 25165824, O_WDOWN = 33554432, O_WUP = 34078720,
               O_ENC = 34603008, O_LN = 36708352, O_BIG = 45096960,
               O_XRES = 78651392, O_HF = 95428608, O_ATTN = 112205824;

  unsigned short* wt_attn   = (unsigned short*)(ws + O_WATTN);
  unsigned short* wt_aproj  = (unsigned short*)(ws + O_WAPROJ);
  unsigned short* wt_ca     = (unsigned short*)(ws + O_WCA);
  unsigned short* wt_caproj = (unsigned short*)(ws + O_WCAPROJ);
  unsigned short* wt_fc     = (unsigned short*)(ws + O_WFC);
  unsigned short* wt_mproj  = (unsigned short*)(ws + O_WMPROJ);
  unsigned short* wt_down   = (unsigned short*)(ws + O_WDOWN);
  unsigned short* wt_up     = (unsigned short*)(ws + O_WUP);
  unsigned short* encbf     = (unsigned short*)(ws + O_ENC);
  unsigned short* lnout     = (unsigned short*)(ws + O_LN);
  unsigned short* hbf       = (unsigned short*)(ws + O_LN);      // reuse after fc consumed
  unsigned short* qkvb      = (unsigned short*)(ws + O_BIG);
  unsigned short* q2b       = (unsigned short*)(ws + O_BIG);
  unsigned short* kvb       = (unsigned short*)(ws + O_BIG + 8388608);
  unsigned short* caout     = (unsigned short*)(ws + O_BIG + 12582912);
  unsigned short* fcout     = (unsigned short*)(ws + O_BIG);
  float*          xres      = (float*)(ws + O_XRES);
  float*          hf        = (float*)(ws + O_HF);
  unsigned short* attnout   = (unsigned short*)(ws + O_ATTN);
  unsigned short* dmid      = (unsigned short*)(ws + O_ATTN);    // reuse after aproj consumed

  dim3 blk(256);

  // 1. weight transposes (f32 [K][N] -> bf16 [N][K])
  k_transpose_cvt<<<dim3(48, 16), blk, 0, stream>>>(attn_w,  wt_attn,   1024, 3072);
  k_transpose_cvt<<<dim3(16, 16), blk, 0, stream>>>(aproj_w, wt_aproj,  1024, 1024);
  k_transpose_cvt<<<dim3(48, 16), blk, 0, stream>>>(ca_w,    wt_ca,     1024, 3072);
  k_transpose_cvt<<<dim3(16, 16), blk, 0, stream>>>(caproj_w,wt_caproj, 1024, 1024);
  k_transpose_cvt<<<dim3(64, 16), blk, 0, stream>>>(fc_w,    wt_fc,     1024, 4096);
  k_transpose_cvt<<<dim3(16, 64), blk, 0, stream>>>(mproj_w, wt_mproj,  4096, 1024);
  k_transpose_cvt<<<dim3(4, 16),  blk, 0, stream>>>(down_w,  wt_down,   1024, 256);
  k_transpose_cvt<<<dim3(16, 4),  blk, 0, stream>>>(up_w,    wt_up,     256,  1024);
  // 2. encoder -> bf16
  k_cvt_bf16<<<dim3(4112), blk, 0, stream>>>(enc, encbf, 1028 * 1024);

  // 3. ln1(x) ; qkv ; self-attn ; aproj + residual(x) -> xres
  k_ln<<<dim3(4096), blk, 0, stream>>>(x, ln1_g, ln1_b, lnout);
  k_gemm<false, false, true, 0><<<dim3(24, 32), blk, 0, stream>>>(
      lnout, wt_attn, attn_b, nullptr, nullptr, nullptr, qkvb, 4096, 3072, 1024);
  k_self_attn<<<dim3(16, 64), blk, 0, stream>>>(qkvb, attnout);
  k_gemm<false, true, false, 1><<<dim3(8, 32), blk, 0, stream>>>(
      attnout, wt_aproj, aproj_b, x, nullptr, xres, nullptr, 4096, 1024, 1024);

  // 4. ln2(xres) ; q2 ; kv(enc) ; cross-attn ; caproj + residual(xres) -> xres
  k_ln<<<dim3(4096), blk, 0, stream>>>(xres, ln2_g, ln2_b, lnout);
  k_gemm<false, false, true, 0><<<dim3(8, 32), blk, 0, stream>>>(
      lnout, wt_ca, ca_b, nullptr, nullptr, nullptr, q2b, 4096, 1024, 1024);
  k_gemm<false, false, true, 0><<<dim3(16, 9), blk, 0, stream>>>(
      encbf, wt_ca + (size_t)1024 * 1024, ca_b + 1024, nullptr, nullptr, nullptr, kvb,
      1028, 2048, 1024);
  k_cross_attn<<<dim3(16, 64), blk, 0, stream>>>(q2b, kvb, caout);
  k_gemm<false, true, false, 1><<<dim3(8, 32), blk, 0, stream>>>(
      caout, wt_caproj, caproj_b, xres, nullptr, xres, nullptr, 4096, 1024, 1024);

  // 5. ln3(xres) ; fc+gelu ; mproj -> h (f32 + bf16)
  k_ln<<<dim3(4096), blk, 0, stream>>>(xres, ln3_g, ln3_b, lnout);
  k_gemm<true, false, true, 0><<<dim3(32, 32), blk, 0, stream>>>(
      lnout, wt_fc, fc_b, nullptr, nullptr, nullptr, fcout, 4096, 4096, 1024);
  k_gemm<false, true, true, 0><<<dim3(8, 32), blk, 0, stream>>>(
      fcout, wt_mproj, mproj_b, nullptr, nullptr, hf, hbf, 4096, 1024, 4096);

  // 6. adapter: down+gelu ; up + up_b + h + xres -> out
  k_gemm<true, false, true, 0><<<dim3(2, 32), blk, 0, stream>>>(
      hbf, wt_down, down_b, nullptr, nullptr, nullptr, dmid, 4096, 256, 1024);
  k_gemm<false, true, false, 2><<<dim3(8, 32), blk, 0, stream>>>(
      dmid, wt_up, up_b, hf, xres, out, nullptr, 4096, 1024, 256);
}

// Round 2
// 545.367 us; speedup vs baseline: 2.2540x; 2.2540x over previous
//
#include <hip/hip_runtime.h>

typedef __attribute__((ext_vector_type(8))) short short8v;
typedef __attribute__((ext_vector_type(8))) unsigned short ushort8v;
typedef __attribute__((ext_vector_type(4))) float f32x4;

__device__ __forceinline__ unsigned short f2b(float f) {
  unsigned int u = __float_as_uint(f);
  unsigned int r = (u + 0x7FFFu + ((u >> 16) & 1u)) >> 16;
  return (unsigned short)r;
}
__device__ __forceinline__ float b2f(unsigned short h) {
  return __uint_as_float(((unsigned int)h) << 16);
}
__device__ __forceinline__ float gelu_f(float x) {
  float z = 0.7978845608028654f * (x + 0.044715f * x * x * x);
  float e = __expf(2.0f * z);
  float t = 1.0f - 2.0f / (e + 1.0f);   // tanh(z), stable at +/-inf
  return 0.5f * x * (1.0f + t);
}
// async global->LDS, 16B per lane. LDS dest must be wave-uniform base + lane*16.
__device__ __forceinline__ void gload16(const void* g, void* l) {
  __builtin_amdgcn_global_load_lds((const __attribute__((address_space(1))) unsigned int*)g,
                                   (__attribute__((address_space(3))) unsigned int*)l,
                                   16, 0, 0);
}

// ---------------- transpose + f32->bf16 convert: w[K][N] -> wt[N][K] ----------------
__global__ __launch_bounds__(256) void k_transpose_cvt(const float* __restrict__ w,
                                                       unsigned short* __restrict__ wt,
                                                       int K, int N) {
  __shared__ float tile[64][65];
  int tn = blockIdx.x * 64, tk = blockIdx.y * 64;
  int c = threadIdx.x & 63, r0 = threadIdx.x >> 6;
#pragma unroll
  for (int p = 0; p < 16; ++p) {
    int r = r0 + p * 4;
    tile[r][c] = w[(size_t)(tk + r) * N + tn + c];
  }
  __syncthreads();
#pragma unroll
  for (int p = 0; p < 16; ++p) {
    int r = r0 + p * 4;
    wt[(size_t)(tn + r) * K + tk + c] = f2b(tile[c][r]);
  }
}

// ---------------- elementwise f32 -> bf16 ----------------
__global__ void k_cvt_bf16(const float* __restrict__ in, unsigned short* __restrict__ out, int n) {
  int i = blockIdx.x * 256 + threadIdx.x;
  if (i < n) out[i] = f2b(in[i]);
}

// ---------------- LayerNorm over C=1024, out bf16 ----------------
__global__ __launch_bounds__(256) void k_ln(const float* __restrict__ in,
                                            const float* __restrict__ g,
                                            const float* __restrict__ b,
                                            unsigned short* __restrict__ out) {
  int row = blockIdx.x;
  const float* x = in + (size_t)row * 1024;
  int t = threadIdx.x;
  float v0 = x[t], v1 = x[t + 256], v2 = x[t + 512], v3 = x[t + 768];
  float s = v0 + v1 + v2 + v3;
  float s2 = v0 * v0 + v1 * v1 + v2 * v2 + v3 * v3;
#pragma unroll
  for (int m = 1; m < 64; m <<= 1) { s += __shfl_xor(s, m); s2 += __shfl_xor(s2, m); }
  __shared__ float rs[4], rs2[4];
  int w = t >> 6;
  if ((t & 63) == 0) { rs[w] = s; rs2[w] = s2; }
  __syncthreads();
  s = rs[0] + rs[1] + rs[2] + rs[3];
  s2 = rs2[0] + rs2[1] + rs2[2] + rs2[3];
  float mean = s * (1.0f / 1024.0f);
  float var = s2 * (1.0f / 1024.0f) - mean * mean;
  float rinv = rsqrtf(var + 1e-5f);
  unsigned short* o = out + (size_t)row * 1024;
  o[t]       = f2b((v0 - mean) * rinv * g[t]       + b[t]);
  o[t + 256] = f2b((v1 - mean) * rinv * g[t + 256] + b[t + 256]);
  o[t + 512] = f2b((v2 - mean) * rinv * g[t + 512] + b[t + 512]);
  o[t + 768] = f2b((v3 - mean) * rinv * g[t + 768] + b[t + 768]);
}

// ---------------- GEMM: out[M][N] = A[M][K](bf16) @ W[N][K](bf16)^T + bias (+gelu)(+res) ----
template <bool GELU, bool WF32, bool WBF16, int NRES>
__global__ __launch_bounds__(256) void k_gemm(const unsigned short* __restrict__ A,
                                              const unsigned short* __restrict__ W,
                                              const float* __restrict__ bias,
                                              const float* __restrict__ res1,
                                              const float* __restrict__ res2,
                                              float* __restrict__ outF,
                                              unsigned short* __restrict__ outB,
                                              int M, int N, int K) {
  __shared__ unsigned short lA[128 * 32];
  __shared__ unsigned short lB[128 * 32];
  int t = threadIdx.x;
  int tile_n = blockIdx.x * 128, tile_m = blockIdx.y * 128;
  int lane = t & 63, w = t >> 6;
  int wm = (w >> 1) * 64, wn = (w & 1) * 64;
  int lr = lane & 15;
  int kh = (lane >> 4) * 8;
  f32x4 acc[4][4];
#pragma unroll
  for (int i = 0; i < 4; ++i)
#pragma unroll
    for (int j = 0; j < 4; ++j) acc[i][j] = f32x4{0.f, 0.f, 0.f, 0.f};

  for (int kt = 0; kt < K; kt += 32) {
    __syncthreads();
#pragma unroll
    for (int r = 0; r < 2; ++r) {
      int e = r * 2048 + t * 8;
      int row = e >> 5, c = e & 31;
      int gr = tile_m + row; gr = gr < M ? gr : M - 1;
      gload16(&A[(size_t)gr * K + kt + c], &lA[e]);
      gload16(&W[(size_t)(tile_n + row) * K + kt + c], &lB[e]);
    }
    __syncthreads();
    short8v af[4], bfr[4];
#pragma unroll
    for (int i = 0; i < 4; ++i) af[i] = *(const short8v*)&lA[(wm + i * 16 + lr) * 32 + kh];
#pragma unroll
    for (int i = 0; i < 4; ++i) bfr[i] = *(const short8v*)&lB[(wn + i * 16 + lr) * 32 + kh];
#pragma unroll
    for (int i = 0; i < 4; ++i)
#pragma unroll
      for (int j = 0; j < 4; ++j)
        acc[i][j] = __builtin_amdgcn_mfma_f32_16x16x32_bf16(af[i], bfr[j], acc[i][j], 0, 0, 0);
  }
  int r0 = (lane >> 4) * 4;
#pragma unroll
  for (int i = 0; i < 4; ++i) {
#pragma unroll
    for (int j = 0; j < 4; ++j) {
      int col = tile_n + wn + j * 16 + lr;
      float bv = bias[col];
#pragma unroll
      for (int q = 0; q < 4; ++q) {
        int row = tile_m + wm + i * 16 + r0 + q;
        if (row < M) {
          float v = acc[i][j][q] + bv;
          if (GELU) v = gelu_f(v);
          size_t o = (size_t)row * N + col;
          if (NRES >= 1) v += res1[o];
          if (NRES >= 2) v += res2[o];
          if (WF32) outF[o] = v;
          if (WBF16) outB[o] = f2b(v);
        }
      }
    }
  }
}

// ---------------- V transpose: src[b*TB+tok][src_off+h*64+d] -> dst[bh][d][tok] ----------------
__global__ __launch_bounds__(256) void k_vtrans(const unsigned short* __restrict__ src,
                                                int src_stride, int src_off, int TB,
                                                unsigned short* __restrict__ dst, int dst_tstride) {
  __shared__ unsigned short tile[64][72];
  int tb = blockIdx.x, bh = blockIdx.y;
  int b = bh >> 4, h = bh & 15;
  int t = threadIdx.x;
  int r = t >> 2, c0 = (t & 3) * 16;
  int tok = tb * 64 + r; if (tok >= TB) tok = TB - 1;
  const unsigned short* s = src + (size_t)(b * TB + tok) * src_stride + src_off + h * 64 + c0;
  *(ushort8v*)&tile[r][c0] = *(const ushort8v*)s;
  *(ushort8v*)&tile[r][c0 + 8] = *(const ushort8v*)(s + 8);
  __syncthreads();
  // write: row d = r, tokens c0..c0+15 of this tile
  unsigned short tmp[16];
#pragma unroll
  for (int j = 0; j < 16; ++j) tmp[j] = tile[c0 + j][r];
  unsigned short* dp = dst + ((size_t)bh * 64 + r) * dst_tstride + tb * 64 + c0;
  *(ushort8v*)dp = *(const ushort8v*)&tmp[0];
  *(ushort8v*)(dp + 8) = *(const ushort8v*)&tmp[8];
}

// ---------------- MFMA flash attention ----------------
// Block 256 thr = 4 waves; block covers 64 q-rows (wave w: rows w*16..+16) of one (b,h).
// K staged [64 key][64 d] (u16 row stride 72), V^T staged [64 d][64 key].
// QK^T: A=Q (m=q,k=d), B=K^T. PV: A=P (m=q,k=key), B=V^T (n=d,k=key).
template <bool CAUSAL>
__global__ __launch_bounds__(256) void k_attn(
    const unsigned short* __restrict__ Qb, int q_stride,
    const unsigned short* __restrict__ Kb, int k_stride, int k_off, int TKR,
    const unsigned short* __restrict__ Vt, int vt_tstride,
    unsigned short* __restrict__ out, int Tk) {
  __shared__ unsigned short Kl[64 * 72];
  __shared__ unsigned short Vl[64 * 72];
  __shared__ unsigned short Pl[4][16 * 72];
  int qb = blockIdx.x, bh = blockIdx.y;
  int b = bh >> 4, h = bh & 15;
  int t = threadIdx.x, lane = t & 63, w = t >> 6;
  int g = lane >> 4, lc = lane & 15;

  int qrow_g = qb * 64 + w * 16 + lc;
  const unsigned short* qp = Qb + (size_t)(b * 1024 + qrow_g) * q_stride + h * 64 + g * 8;
  short8v aq0 = *(const short8v*)qp;
  short8v aq1 = *(const short8v*)(qp + 32);

  f32x4 o[4];
  float m_[4], l_[4];
#pragma unroll
  for (int dt = 0; dt < 4; ++dt) o[dt] = f32x4{0.f, 0.f, 0.f, 0.f};
#pragma unroll
  for (int r = 0; r < 4; ++r) { m_[r] = -3.0e38f; l_[r] = 0.0f; }

  int srow = t >> 2;            // staging: key row (K) / d row (Vt)
  int sc = (t & 3) * 16;
  int ntiles = CAUSAL ? (qb + 1) : ((Tk + 63) >> 6);

  for (int kt = 0; kt < ntiles; ++kt) {
    __syncthreads();
    {
      int kg = kt * 64 + srow;
      if (!CAUSAL && kg >= Tk) kg = Tk - 1;
      const unsigned short* ks = Kb + (size_t)(b * TKR + kg) * k_stride + k_off + h * 64 + sc;
      *(ushort8v*)&Kl[srow * 72 + sc]     = *(const ushort8v*)ks;
      *(ushort8v*)&Kl[srow * 72 + sc + 8] = *(const ushort8v*)(ks + 8);
      const unsigned short* vs = Vt + ((size_t)bh * 64 + srow) * vt_tstride + kt * 64 + sc;
      *(ushort8v*)&Vl[srow * 72 + sc]     = *(const ushort8v*)vs;
      *(ushort8v*)&Vl[srow * 72 + sc + 8] = *(const ushort8v*)(vs + 8);
    }
    __syncthreads();

    f32x4 s[4];
#pragma unroll
    for (int jt = 0; jt < 4; ++jt) {
      short8v bk0 = *(const short8v*)&Kl[(jt * 16 + lc) * 72 + g * 8];
      short8v bk1 = *(const short8v*)&Kl[(jt * 16 + lc) * 72 + g * 8 + 32];
      f32x4 acc = f32x4{0.f, 0.f, 0.f, 0.f};
      acc = __builtin_amdgcn_mfma_f32_16x16x32_bf16(aq0, bk0, acc, 0, 0, 0);
      acc = __builtin_amdgcn_mfma_f32_16x16x32_bf16(aq1, bk1, acc, 0, 0, 0);
      s[jt] = acc;
    }
#pragma unroll
    for (int jt = 0; jt < 4; ++jt)
#pragma unroll
      for (int r = 0; r < 4; ++r) {
        float sv = s[jt][r] * 0.125f;
        bool masked = CAUSAL ? (kt == qb && (jt * 16 + lc) > (w * 16 + g * 4 + r))
                             : (kt * 64 + jt * 16 + lc >= Tk);
        s[jt][r] = masked ? -3.0e38f : sv;
      }
    float f[4];
#pragma unroll
    for (int r = 0; r < 4; ++r) {
      float mx = fmaxf(fmaxf(s[0][r], s[1][r]), fmaxf(s[2][r], s[3][r]));
      mx = fmaxf(mx, __shfl_xor(mx, 1));
      mx = fmaxf(mx, __shfl_xor(mx, 2));
      mx = fmaxf(mx, __shfl_xor(mx, 4));
      mx = fmaxf(mx, __shfl_xor(mx, 8));
      float mnew = fmaxf(m_[r], mx);
      f[r] = __expf(m_[r] - mnew);
      m_[r] = mnew;
      float rsum = 0.0f;
#pragma unroll
      for (int jt = 0; jt < 4; ++jt) {
        float p = __expf(s[jt][r] - mnew);
        s[jt][r] = p;
        rsum += p;
      }
      rsum += __shfl_xor(rsum, 1);
      rsum += __shfl_xor(rsum, 2);
      rsum += __shfl_xor(rsum, 4);
      rsum += __shfl_xor(rsum, 8);
      l_[r] = l_[r] * f[r] + rsum;
    }
#pragma unroll
    for (int dt = 0; dt < 4; ++dt)
#pragma unroll
      for (int r = 0; r < 4; ++r) o[dt][r] *= f[r];
    // P (f32, C-layout) -> bf16 in LDS -> A-layout fragments
#pragma unroll
    for (int jt = 0; jt < 4; ++jt)
#pragma unroll
      for (int r = 0; r < 4; ++r)
        Pl[w][(g * 4 + r) * 72 + jt * 16 + lc] = f2b(s[jt][r]);
    short8v ap0 = *(const short8v*)&Pl[w][lc * 72 + g * 8];
    short8v ap1 = *(const short8v*)&Pl[w][lc * 72 + g * 8 + 32];
#pragma unroll
    for (int dt = 0; dt < 4; ++dt) {
      short8v bv0 = *(const short8v*)&Vl[(dt * 16 + lc) * 72 + g * 8];
      short8v bv1 = *(const short8v*)&Vl[(dt * 16 + lc) * 72 + g * 8 + 32];
      o[dt] = __builtin_amdgcn_mfma_f32_16x16x32_bf16(ap0, bv0, o[dt], 0, 0, 0);
      o[dt] = __builtin_amdgcn_mfma_f32_16x16x32_bf16(ap1, bv1, o[dt], 0, 0, 0);
    }
  }
  size_t orow = (size_t)(b * 1024 + qb * 64 + w * 16) * 1024 + h * 64;
#pragma unroll
  for (int r = 0; r < 4; ++r) {
    float inv = 1.0f / l_[r];
#pragma unroll
    for (int dt = 0; dt < 4; ++dt)
      out[orow + (size_t)(g * 4 + r) * 1024 + dt * 16 + lc] = f2b(o[dt][r] * inv);
  }
}

extern "C" void kernel_launch(void* const* d_in, const int* in_sizes, int n_in,
                              void* d_out, int out_size, void* d_ws, size_t ws_size,
                              hipStream_t stream) {
  (void)in_sizes; (void)n_in; (void)out_size; (void)ws_size;
  const float* x       = (const float*)d_in[0];
  const float* enc     = (const float*)d_in[1];
  const float* ln1_g   = (const float*)d_in[3];
  const float* ln1_b   = (const float*)d_in[4];
  const float* ln2_g   = (const float*)d_in[5];
  const float* ln2_b   = (const float*)d_in[6];
  const float* ln3_g   = (const float*)d_in[7];
  const float* ln3_b   = (const float*)d_in[8];
  const float* attn_w  = (const float*)d_in[9];
  const float* attn_b  = (const float*)d_in[10];
  const float* aproj_w = (const float*)d_in[11];
  const float* aproj_b = (const float*)d_in[12];
  const float* ca_w    = (const float*)d_in[13];
  const float* ca_b    = (const float*)d_in[14];
  const float* caproj_w= (const float*)d_in[15];
  const float* caproj_b= (const float*)d_in[16];
  const float* fc_w    = (const float*)d_in[17];
  const float* fc_b    = (const float*)d_in[18];
  const float* mproj_w = (const float*)d_in[19];
  const float* mproj_b = (const float*)d_in[20];
  const float* down_w  = (const float*)d_in[21];
  const float* down_b  = (const float*)d_in[22];
  const float* up_w    = (const float*)d_in[23];
  const float* up_b    = (const float*)d_in[24];
  float* out = (float*)d_out;
  char* ws = (char*)d_ws;

  const size_t O_WATTN = 0, O_WAPROJ = 6291456, O_WCA = 8388608, O_WCAPROJ = 14680064,
               O_WFC = 16777216, O_WMPROJ = 25165824, O_WDOWN = 33554432, O_WUP = 34078720,
               O_ENC = 34603008, O_LN = 36708352, O_BIG = 45096960,
               O_XRES = 78651392, O_HF = 95428608, O_ATTN = 112205824;

  unsigned short* wt_attn   = (unsigned short*)(ws + O_WATTN);
  unsigned short* wt_aproj  = (unsigned short*)(ws + O_WAPROJ);
  unsigned short* wt_ca     = (unsigned short*)(ws + O_WCA);
  unsigned short* wt_caproj = (unsigned short*)(ws + O_WCAPROJ);
  unsigned short* wt_fc     = (unsigned short*)(ws + O_WFC);
  unsigned short* wt_mproj  = (unsigned short*)(ws + O_WMPROJ);
  unsigned short* wt_down   = (unsigned short*)(ws + O_WDOWN);
  unsigned short* wt_up     = (unsigned short*)(ws + O_WUP);
  unsigned short* encbf     = (unsigned short*)(ws + O_ENC);
  unsigned short* lnout     = (unsigned short*)(ws + O_LN);
  unsigned short* hbf       = (unsigned short*)(ws + O_LN);            // after fc consumed
  unsigned short* qkvb      = (unsigned short*)(ws + O_BIG);
  unsigned short* vt_self   = (unsigned short*)(ws + O_BIG + 25165824); // alive with qkvb
  unsigned short* q2b       = (unsigned short*)(ws + O_BIG);           // after self path done
  unsigned short* kvb       = (unsigned short*)(ws + O_BIG + 8388608);
  unsigned short* vt_cross  = (unsigned short*)(ws + O_BIG + 12599296);
  unsigned short* caout     = (unsigned short*)(ws + O_BIG + 15220736);
  unsigned short* fcout     = (unsigned short*)(ws + O_BIG);           // after cross path done
  float*          xres      = (float*)(ws + O_XRES);
  float*          hf        = (float*)(ws + O_HF);
  unsigned short* attnout   = (unsigned short*)(ws + O_ATTN);
  unsigned short* dmid      = (unsigned short*)(ws + O_ATTN);          // after aproj consumed

  dim3 blk(256);

  // 1. weight transposes (f32 [K][N] -> bf16 [N][K])
  k_transpose_cvt<<<dim3(48, 16), blk, 0, stream>>>(attn_w,  wt_attn,   1024, 3072);
  k_transpose_cvt<<<dim3(16, 16), blk, 0, stream>>>(aproj_w, wt_aproj,  1024, 1024);
  k_transpose_cvt<<<dim3(48, 16), blk, 0, stream>>>(ca_w,    wt_ca,     1024, 3072);
  k_transpose_cvt<<<dim3(16, 16), blk, 0, stream>>>(caproj_w,wt_caproj, 1024, 1024);
  k_transpose_cvt<<<dim3(64, 16), blk, 0, stream>>>(fc_w,    wt_fc,     1024, 4096);
  k_transpose_cvt<<<dim3(16, 64), blk, 0, stream>>>(mproj_w, wt_mproj,  4096, 1024);
  k_transpose_cvt<<<dim3(4, 16),  blk, 0, stream>>>(down_w,  wt_down,   1024, 256);
  k_transpose_cvt<<<dim3(16, 4),  blk, 0, stream>>>(up_w,    wt_up,     256,  1024);
  // 2. encoder -> bf16
  k_cvt_bf16<<<dim3(4112), blk, 0, stream>>>(enc, encbf, 1028 * 1024);

  // 3. ln1(x) ; qkv ; V-transpose ; self-attn ; aproj + residual(x) -> xres
  k_ln<<<dim3(4096), blk, 0, stream>>>(x, ln1_g, ln1_b, lnout);
  k_gemm<false, false, true, 0><<<dim3(24, 32), blk, 0, stream>>>(
      lnout, wt_attn, attn_b, nullptr, nullptr, nullptr, qkvb, 4096, 3072, 1024);
  k_vtrans<<<dim3(16, 64), blk, 0, stream>>>(qkvb, 3072, 2048, 1024, vt_self, 1024);
  k_attn<true><<<dim3(16, 64), blk, 0, stream>>>(
      qkvb, 3072, qkvb, 3072, 1024, 1024, vt_self, 1024, attnout, 1024);
  k_gemm<false, true, false, 1><<<dim3(8, 32), blk, 0, stream>>>(
      attnout, wt_aproj, aproj_b, x, nullptr, xres, nullptr, 4096, 1024, 1024);

  // 4. ln2(xres) ; q2 ; kv(enc) ; V-transpose ; cross-attn ; caproj + residual -> xres
  k_ln<<<dim3(4096), blk, 0, stream>>>(xres, ln2_g, ln2_b, lnout);
  k_gemm<false, false, true, 0><<<dim3(8, 32), blk, 0, stream>>>(
      lnout, wt_ca, ca_b, nullptr, nullptr, nullptr, q2b, 4096, 1024, 1024);
  k_gemm<false, false, true, 0><<<dim3(16, 9), blk, 0, stream>>>(
      encbf, wt_ca + (size_t)1024 * 1024, ca_b + 1024, nullptr, nullptr, nullptr, kvb,
      1028, 2048, 1024);
  k_vtrans<<<dim3(5, 64), blk, 0, stream>>>(kvb, 2048, 1024, 257, vt_cross, 320);
  k_attn<false><<<dim3(16, 64), blk, 0, stream>>>(
      q2b, 1024, kvb, 2048, 0, 257, vt_cross, 320, caout, 257);
  k_gemm<false, true, false, 1><<<dim3(8, 32), blk, 0, stream>>>(
      caout, wt_caproj, caproj_b, xres, nullptr, xres, nullptr, 4096, 1024, 1024);

  // 5. ln3(xres) ; fc+gelu ; mproj -> h (f32 + bf16)
  k_ln<<<dim3(4096), blk, 0, stream>>>(xres, ln3_g, ln3_b, lnout);
  k_gemm<true, false, true, 0><<<dim3(32, 32), blk, 0, stream>>>(
      lnout, wt_fc, fc_b, nullptr, nullptr, nullptr, fcout, 4096, 4096, 1024);
  k_gemm<false, true, true, 0><<<dim3(8, 32), blk, 0, stream>>>(
      fcout, wt_mproj, mproj_b, nullptr, nullptr, hf, hbf, 4096, 1024, 4096);

  // 6. adapter: down+gelu ; up + up_b + h + xres -> out
  k_gemm<true, false, true, 0><<<dim3(2, 32), blk, 0, stream>>>(
      hbf, wt_down, down_b, nullptr, nullptr, nullptr, dmid, 4096, 256, 1024);
  k_gemm<false, true, false, 2><<<dim3(8, 32), blk, 0, stream>>>(
      dmid, wt_up, up_b, hf, xres, out, nullptr, 4096, 1024, 256);
}

// Round 3
// 473.854 us; speedup vs baseline: 2.5941x; 1.1509x over previous
//
#include <hip/hip_runtime.h>

typedef __attribute__((ext_vector_type(8))) short short8v;
typedef __attribute__((ext_vector_type(8))) unsigned short ushort8v;
typedef __attribute__((ext_vector_type(4))) float f32x4;

__device__ __forceinline__ unsigned short f2b(float f) {
  unsigned int u = __float_as_uint(f);
  unsigned int r = (u + 0x7FFFu + ((u >> 16) & 1u)) >> 16;
  return (unsigned short)r;
}
__device__ __forceinline__ float b2f(unsigned short h) {
  return __uint_as_float(((unsigned int)h) << 16);
}
__device__ __forceinline__ float gelu_f(float x) {
  float z = 0.7978845608028654f * (x + 0.044715f * x * x * x);
  float e = __expf(2.0f * z);
  float t = 1.0f - 2.0f / (e + 1.0f);   // tanh(z), stable at +/-inf
  return 0.5f * x * (1.0f + t);
}
// async global->LDS, 16B per lane. LDS dest must be wave-uniform base + lane*16.
__device__ __forceinline__ void gload16(const void* g, void* l) {
  __builtin_amdgcn_global_load_lds((const __attribute__((address_space(1))) unsigned int*)g,
                                   (__attribute__((address_space(3))) unsigned int*)l,
                                   16, 0, 0);
}

// ---------------- transpose + f32->bf16 convert: w[K][N] -> wt[N][K] ----------------
__global__ __launch_bounds__(256) void k_transpose_cvt(const float* __restrict__ w,
                                                       unsigned short* __restrict__ wt,
                                                       int K, int N) {
  __shared__ float tile[64][65];
  int tn = blockIdx.x * 64, tk = blockIdx.y * 64;
  int c = threadIdx.x & 63, r0 = threadIdx.x >> 6;
#pragma unroll
  for (int p = 0; p < 16; ++p) {
    int r = r0 + p * 4;
    tile[r][c] = w[(size_t)(tk + r) * N + tn + c];
  }
  __syncthreads();
#pragma unroll
  for (int p = 0; p < 16; ++p) {
    int r = r0 + p * 4;
    wt[(size_t)(tn + r) * K + tk + c] = f2b(tile[c][r]);
  }
}

// ---------------- elementwise f32 -> bf16 ----------------
__global__ void k_cvt_bf16(const float* __restrict__ in, unsigned short* __restrict__ out, int n) {
  int i = blockIdx.x * 256 + threadIdx.x;
  if (i < n) out[i] = f2b(in[i]);
}

// ---------------- LayerNorm over C=1024, out bf16 ----------------
__global__ __launch_bounds__(256) void k_ln(const float* __restrict__ in,
                                            const float* __restrict__ g,
                                            const float* __restrict__ b,
                                            unsigned short* __restrict__ out) {
  int row = blockIdx.x;
  const float* x = in + (size_t)row * 1024;
  int t = threadIdx.x;
  float v0 = x[t], v1 = x[t + 256], v2 = x[t + 512], v3 = x[t + 768];
  float s = v0 + v1 + v2 + v3;
  float s2 = v0 * v0 + v1 * v1 + v2 * v2 + v3 * v3;
#pragma unroll
  for (int m = 1; m < 64; m <<= 1) { s += __shfl_xor(s, m); s2 += __shfl_xor(s2, m); }
  __shared__ float rs[4], rs2[4];
  int w = t >> 6;
  if ((t & 63) == 0) { rs[w] = s; rs2[w] = s2; }
  __syncthreads();
  s = rs[0] + rs[1] + rs[2] + rs[3];
  s2 = rs2[0] + rs2[1] + rs2[2] + rs2[3];
  float mean = s * (1.0f / 1024.0f);
  float var = s2 * (1.0f / 1024.0f) - mean * mean;
  float rinv = rsqrtf(var + 1e-5f);
  unsigned short* o = out + (size_t)row * 1024;
  o[t]       = f2b((v0 - mean) * rinv * g[t]       + b[t]);
  o[t + 256] = f2b((v1 - mean) * rinv * g[t + 256] + b[t + 256]);
  o[t + 512] = f2b((v2 - mean) * rinv * g[t + 512] + b[t + 512]);
  o[t + 768] = f2b((v3 - mean) * rinv * g[t + 768] + b[t + 768]);
}

// ---------------- GEMM: out[M][N] = A[M][K](bf16) @ W[N][K](bf16)^T + bias (+gelu)(+res) ----
// 128x128 tile, BK=32, 2-phase double-buffered LDS with counted vmcnt prefetch (T3/T4).
// LDS chunk-swizzle: row r, 16B-chunk slot s holds global chunk s ^ ((r>>1)&3)
// (pre-swizzled global source; linear gload_lds dest; XOR on read) -> 2-way banks (free).
template <bool GELU, bool WF32, bool WBF16, int NRES>
__global__ __launch_bounds__(256) void k_gemm(const unsigned short* __restrict__ A,
                                              const unsigned short* __restrict__ W,
                                              const float* __restrict__ bias,
                                              const float* __restrict__ res1,
                                              const float* __restrict__ res2,
                                              float* __restrict__ outF,
                                              unsigned short* __restrict__ outB,
                                              int M, int N, int K) {
  __shared__ unsigned short sm[2][8192];   // per buf: A = [0,4096) u16, B = [4096,8192)
  int t = threadIdx.x;
  int tile_n = blockIdx.x * 128, tile_m = blockIdx.y * 128;
  int lane = t & 63, w = t >> 6;
  int wm = (w >> 1) * 64, wn = (w & 1) * 64;
  int lr = lane & 15;
  int kc = lane >> 4;           // 16B chunk index within the 32-elem K-slab

  // staging: thread t owns rows (t>>2) and 64+(t>>2), chunk s0 = t&3 of each row
  int row0 = t >> 2, row1 = 64 + (t >> 2);
  int s0 = t & 3;
  int colA0 = (s0 ^ ((row0 >> 1) & 3)) * 8;
  int colA1 = (s0 ^ ((row1 >> 1) & 3)) * 8;
  int grA0 = tile_m + row0; if (grA0 >= M) grA0 = M - 1;
  int grA1 = tile_m + row1; if (grA1 >= M) grA1 = M - 1;
  const unsigned short* gA0 = A + (size_t)grA0 * K + colA0;
  const unsigned short* gA1 = A + (size_t)grA1 * K + colA1;
  const unsigned short* gB0 = W + (size_t)(tile_n + row0) * K + colA0;
  const unsigned short* gB1 = W + (size_t)(tile_n + row1) * K + colA1;

  f32x4 acc[4][4];
#pragma unroll
  for (int i = 0; i < 4; ++i)
#pragma unroll
    for (int j = 0; j < 4; ++j) acc[i][j] = f32x4{0.f, 0.f, 0.f, 0.f};

  int nsteps = K >> 5;
  // prologue: stage tile 0 into buf 0
  gload16(gA0, &sm[0][t * 8]);
  gload16(gA1, &sm[0][2048 + t * 8]);
  gload16(gB0, &sm[0][4096 + t * 8]);
  gload16(gB1, &sm[0][6144 + t * 8]);

  for (int ks = 0; ks < nsteps; ++ks) {
    int cur = ks & 1, nxt = cur ^ 1;
    if (ks + 1 < nsteps) {
      int off = (ks + 1) << 5;
      gload16(gA0 + off, &sm[nxt][t * 8]);
      gload16(gA1 + off, &sm[nxt][2048 + t * 8]);
      gload16(gB0 + off, &sm[nxt][4096 + t * 8]);
      gload16(gB1 + off, &sm[nxt][6144 + t * 8]);
      asm volatile("s_waitcnt vmcnt(4)" ::: "memory");   // old tile landed; new 4 stay in flight
    } else {
      asm volatile("s_waitcnt vmcnt(0)" ::: "memory");
    }
    __builtin_amdgcn_s_barrier();
    asm volatile("" ::: "memory");
    const unsigned short* buf = &sm[cur][0];
    short8v af[4], bfr[4];
#pragma unroll
    for (int i = 0; i < 4; ++i) {
      int rA = wm + i * 16 + lr;
      int sl = (kc ^ ((rA >> 1) & 3)) * 8;
      af[i] = *(const short8v*)&buf[rA * 32 + sl];
    }
#pragma unroll
    for (int j = 0; j < 4; ++j) {
      int rB = wn + j * 16 + lr;
      int sl = (kc ^ ((rB >> 1) & 3)) * 8;
      bfr[j] = *(const short8v*)&buf[4096 + rB * 32 + sl];
    }
#pragma unroll
    for (int i = 0; i < 4; ++i)
#pragma unroll
      for (int j = 0; j < 4; ++j)
        acc[i][j] = __builtin_amdgcn_mfma_f32_16x16x32_bf16(af[i], bfr[j], acc[i][j], 0, 0, 0);
    asm volatile("" ::: "memory");
    __builtin_amdgcn_s_barrier();   // all waves done reading buf[cur]; next iter may overwrite it
  }

  int r0 = (lane >> 4) * 4;
#pragma unroll
  for (int i = 0; i < 4; ++i) {
#pragma unroll
    for (int j = 0; j < 4; ++j) {
      int col = tile_n + wn + j * 16 + lr;
      float bv = bias[col];
#pragma unroll
      for (int q = 0; q < 4; ++q) {
        int row = tile_m + wm + i * 16 + r0 + q;
        if (row < M) {
          float v = acc[i][j][q] + bv;
          if (GELU) v = gelu_f(v);
          size_t o = (size_t)row * N + col;
          if (NRES >= 1) v += res1[o];
          if (NRES >= 2) v += res2[o];
          if (WF32) outF[o] = v;
          if (WBF16) outB[o] = f2b(v);
        }
      }
    }
  }
}

// ---------------- V transpose: src[b*TB+tok][src_off+h*64+d] -> dst[bh][d][tok] ----------------
__global__ __launch_bounds__(256) void k_vtrans(const unsigned short* __restrict__ src,
                                                int src_stride, int src_off, int TB,
                                                unsigned short* __restrict__ dst, int dst_tstride) {
  __shared__ unsigned short tile[64][72];
  int tb = blockIdx.x, bh = blockIdx.y;
  int b = bh >> 4, h = bh & 15;
  int t = threadIdx.x;
  int r = t >> 2, c0 = (t & 3) * 16;
  int tok = tb * 64 + r; if (tok >= TB) tok = TB - 1;
  const unsigned short* s = src + (size_t)(b * TB + tok) * src_stride + src_off + h * 64 + c0;
  *(ushort8v*)&tile[r][c0] = *(const ushort8v*)s;
  *(ushort8v*)&tile[r][c0 + 8] = *(const ushort8v*)(s + 8);
  __syncthreads();
  unsigned short tmp[16];
#pragma unroll
  for (int j = 0; j < 16; ++j) tmp[j] = tile[c0 + j][r];
  unsigned short* dp = dst + ((size_t)bh * 64 + r) * dst_tstride + tb * 64 + c0;
  *(ushort8v*)dp = *(const ushort8v*)&tmp[0];
  *(ushort8v*)(dp + 8) = *(const ushort8v*)&tmp[8];
}

// ---------------- MFMA flash attention ----------------
template <bool CAUSAL>
__global__ __launch_bounds__(256) void k_attn(
    const unsigned short* __restrict__ Qb, int q_stride,
    const unsigned short* __restrict__ Kb, int k_stride, int k_off, int TKR,
    const unsigned short* __restrict__ Vt, int vt_tstride,
    unsigned short* __restrict__ out, int Tk) {
  __shared__ unsigned short Kl[64 * 72];
  __shared__ unsigned short Vl[64 * 72];
  __shared__ unsigned short Pl[4][16 * 72];
  int qb = blockIdx.x, bh = blockIdx.y;
  int b = bh >> 4, h = bh & 15;
  int t = threadIdx.x, lane = t & 63, w = t >> 6;
  int g = lane >> 4, lc = lane & 15;

  int qrow_g = qb * 64 + w * 16 + lc;
  const unsigned short* qp = Qb + (size_t)(b * 1024 + qrow_g) * q_stride + h * 64 + g * 8;
  short8v aq0 = *(const short8v*)qp;
  short8v aq1 = *(const short8v*)(qp + 32);

  f32x4 o[4];
  float m_[4], l_[4];
#pragma unroll
  for (int dt = 0; dt < 4; ++dt) o[dt] = f32x4{0.f, 0.f, 0.f, 0.f};
#pragma unroll
  for (int r = 0; r < 4; ++r) { m_[r] = -3.0e38f; l_[r] = 0.0f; }

  int srow = t >> 2;
  int sc = (t & 3) * 16;
  int ntiles = CAUSAL ? (qb + 1) : ((Tk + 63) >> 6);

  for (int kt = 0; kt < ntiles; ++kt) {
    __syncthreads();
    {
      int kg = kt * 64 + srow;
      if (!CAUSAL && kg >= Tk) kg = Tk - 1;
      const unsigned short* ks = Kb + (size_t)(b * TKR + kg) * k_stride + k_off + h * 64 + sc;
      *(ushort8v*)&Kl[srow * 72 + sc]     = *(const ushort8v*)ks;
      *(ushort8v*)&Kl[srow * 72 + sc + 8] = *(const ushort8v*)(ks + 8);
      const unsigned short* vs = Vt + ((size_t)bh * 64 + srow) * vt_tstride + kt * 64 + sc;
      *(ushort8v*)&Vl[srow * 72 + sc]     = *(const ushort8v*)vs;
      *(ushort8v*)&Vl[srow * 72 + sc + 8] = *(const ushort8v*)(vs + 8);
    }
    __syncthreads();

    f32x4 s[4];
#pragma unroll
    for (int jt = 0; jt < 4; ++jt) {
      short8v bk0 = *(const short8v*)&Kl[(jt * 16 + lc) * 72 + g * 8];
      short8v bk1 = *(const short8v*)&Kl[(jt * 16 + lc) * 72 + g * 8 + 32];
      f32x4 acc = f32x4{0.f, 0.f, 0.f, 0.f};
      acc = __builtin_amdgcn_mfma_f32_16x16x32_bf16(aq0, bk0, acc, 0, 0, 0);
      acc = __builtin_amdgcn_mfma_f32_16x16x32_bf16(aq1, bk1, acc, 0, 0, 0);
      s[jt] = acc;
    }
#pragma unroll
    for (int jt = 0; jt < 4; ++jt)
#pragma unroll
      for (int r = 0; r < 4; ++r) {
        float sv = s[jt][r] * 0.125f;
        bool masked = CAUSAL ? (kt == qb && (jt * 16 + lc) > (w * 16 + g * 4 + r))
                             : (kt * 64 + jt * 16 + lc >= Tk);
        s[jt][r] = masked ? -3.0e38f : sv;
      }
    float f[4];
#pragma unroll
    for (int r = 0; r < 4; ++r) {
      float mx = fmaxf(fmaxf(s[0][r], s[1][r]), fmaxf(s[2][r], s[3][r]));
      mx = fmaxf(mx, __shfl_xor(mx, 1));
      mx = fmaxf(mx, __shfl_xor(mx, 2));
      mx = fmaxf(mx, __shfl_xor(mx, 4));
      mx = fmaxf(mx, __shfl_xor(mx, 8));
      float mnew = fmaxf(m_[r], mx);
      f[r] = __expf(m_[r] - mnew);
      m_[r] = mnew;
      float rsum = 0.0f;
#pragma unroll
      for (int jt = 0; jt < 4; ++jt) {
        float p = __expf(s[jt][r] - mnew);
        s[jt][r] = p;
        rsum += p;
      }
      rsum += __shfl_xor(rsum, 1);
      rsum += __shfl_xor(rsum, 2);
      rsum += __shfl_xor(rsum, 4);
      rsum += __shfl_xor(rsum, 8);
      l_[r] = l_[r] * f[r] + rsum;
    }
#pragma unroll
    for (int dt = 0; dt < 4; ++dt)
#pragma unroll
      for (int r = 0; r < 4; ++r) o[dt][r] *= f[r];
#pragma unroll
    for (int jt = 0; jt < 4; ++jt)
#pragma unroll
      for (int r = 0; r < 4; ++r)
        Pl[w][(g * 4 + r) * 72 + jt * 16 + lc] = f2b(s[jt][r]);
    short8v ap0 = *(const short8v*)&Pl[w][lc * 72 + g * 8];
    short8v ap1 = *(const short8v*)&Pl[w][lc * 72 + g * 8 + 32];
#pragma unroll
    for (int dt = 0; dt < 4; ++dt) {
      short8v bv0 = *(const short8v*)&Vl[(dt * 16 + lc) * 72 + g * 8];
      short8v bv1 = *(const short8v*)&Vl[(dt * 16 + lc) * 72 + g * 8 + 32];
      o[dt] = __builtin_amdgcn_mfma_f32_16x16x32_bf16(ap0, bv0, o[dt], 0, 0, 0);
      o[dt] = __builtin_amdgcn_mfma_f32_16x16x32_bf16(ap1, bv1, o[dt], 0, 0, 0);
    }
  }
  size_t orow = (size_t)(b * 1024 + qb * 64 + w * 16) * 1024 + h * 64;
#pragma unroll
  for (int r = 0; r < 4; ++r) {
    float inv = 1.0f / l_[r];
#pragma unroll
    for (int dt = 0; dt < 4; ++dt)
      out[orow + (size_t)(g * 4 + r) * 1024 + dt * 16 + lc] = f2b(o[dt][r] * inv);
  }
}

extern "C" void kernel_launch(void* const* d_in, const int* in_sizes, int n_in,
                              void* d_out, int out_size, void* d_ws, size_t ws_size,
                              hipStream_t stream) {
  (void)in_sizes; (void)n_in; (void)out_size; (void)ws_size;
  const float* x       = (const float*)d_in[0];
  const float* enc     = (const float*)d_in[1];
  const float* ln1_g   = (const float*)d_in[3];
  const float* ln1_b   = (const float*)d_in[4];
  const float* ln2_g   = (const float*)d_in[5];
  const float* ln2_b   = (const float*)d_in[6];
  const float* ln3_g   = (const float*)d_in[7];
  const float* ln3_b   = (const float*)d_in[8];
  const float* attn_w  = (const float*)d_in[9];
  const float* attn_b  = (const float*)d_in[10];
  const float* aproj_w = (const float*)d_in[11];
  const float* aproj_b = (const float*)d_in[12];
  const float* ca_w    = (const float*)d_in[13];
  const float* ca_b    = (const float*)d_in[14];
  const float* caproj_w= (const float*)d_in[15];
  const float* caproj_b= (const float*)d_in[16];
  const float* fc_w    = (const float*)d_in[17];
  const float* fc_b    = (const float*)d_in[18];
  const float* mproj_w = (const float*)d_in[19];
  const float* mproj_b = (const float*)d_in[20];
  const float* down_w  = (const float*)d_in[21];
  const float* down_b  = (const float*)d_in[22];
  const float* up_w    = (const float*)d_in[23];
  const float* up_b    = (const float*)d_in[24];
  float* out = (float*)d_out;
  char* ws = (char*)d_ws;

  const size_t O_WATTN = 0, O_WAPROJ = 6291456, O_WCA = 8388608, O_WCAPROJ = 14680064,
               O_WFC = 16777216, O_WMPROJ = 25165824, O_WDOWN = 33554432, O_WUP = 34078720,
               O_ENC = 34603008, O_LN = 36708352, O_BIG = 45096960,
               O_XRES = 78651392, O_HF = 95428608, O_ATTN = 112205824;

  unsigned short* wt_attn   = (unsigned short*)(ws + O_WATTN);
  unsigned short* wt_aproj  = (unsigned short*)(ws + O_WAPROJ);
  unsigned short* wt_ca     = (unsigned short*)(ws + O_WCA);
  unsigned short* wt_caproj = (unsigned short*)(ws + O_WCAPROJ);
  unsigned short* wt_fc     = (unsigned short*)(ws + O_WFC);
  unsigned short* wt_mproj  = (unsigned short*)(ws + O_WMPROJ);
  unsigned short* wt_down   = (unsigned short*)(ws + O_WDOWN);
  unsigned short* wt_up     = (unsigned short*)(ws + O_WUP);
  unsigned short* encbf     = (unsigned short*)(ws + O_ENC);
  unsigned short* lnout     = (unsigned short*)(ws + O_LN);
  unsigned short* hbf       = (unsigned short*)(ws + O_LN);            // after fc consumed
  unsigned short* qkvb      = (unsigned short*)(ws + O_BIG);
  unsigned short* vt_self   = (unsigned short*)(ws + O_BIG + 25165824); // alive with qkvb
  unsigned short* q2b       = (unsigned short*)(ws + O_BIG);           // after self path done
  unsigned short* kvb       = (unsigned short*)(ws + O_BIG + 8388608);
  unsigned short* vt_cross  = (unsigned short*)(ws + O_BIG + 12599296);
  unsigned short* caout     = (unsigned short*)(ws + O_BIG + 15220736);
  unsigned short* fcout     = (unsigned short*)(ws + O_BIG);           // after cross path done
  float*          xres      = (float*)(ws + O_XRES);
  float*          hf        = (float*)(ws + O_HF);
  unsigned short* attnout   = (unsigned short*)(ws + O_ATTN);
  unsigned short* dmid      = (unsigned short*)(ws + O_ATTN);          // after aproj consumed

  dim3 blk(256);

  // 1. weight transposes (f32 [K][N] -> bf16 [N][K])
  k_transpose_cvt<<<dim3(48, 16), blk, 0, stream>>>(attn_w,  wt_attn,   1024, 3072);
  k_transpose_cvt<<<dim3(16, 16), blk, 0, stream>>>(aproj_w, wt_aproj,  1024, 1024);
  k_transpose_cvt<<<dim3(48, 16), blk, 0, stream>>>(ca_w,    wt_ca,     1024, 3072);
  k_transpose_cvt<<<dim3(16, 16), blk, 0, stream>>>(caproj_w,wt_caproj, 1024, 1024);
  k_transpose_cvt<<<dim3(64, 16), blk, 0, stream>>>(fc_w,    wt_fc,     1024, 4096);
  k_transpose_cvt<<<dim3(16, 64), blk, 0, stream>>>(mproj_w, wt_mproj,  4096, 1024);
  k_transpose_cvt<<<dim3(4, 16),  blk, 0, stream>>>(down_w,  wt_down,   1024, 256);
  k_transpose_cvt<<<dim3(16, 4),  blk, 0, stream>>>(up_w,    wt_up,     256,  1024);
  // 2. encoder -> bf16
  k_cvt_bf16<<<dim3(4112), blk, 0, stream>>>(enc, encbf, 1028 * 1024);

  // 3. ln1(x) ; qkv ; V-transpose ; self-attn ; aproj + residual(x) -> xres
  k_ln<<<dim3(4096), blk, 0, stream>>>(x, ln1_g, ln1_b, lnout);
  k_gemm<false, false, true, 0><<<dim3(24, 32), blk, 0, stream>>>(
      lnout, wt_attn, attn_b, nullptr, nullptr, nullptr, qkvb, 4096, 3072, 1024);
  k_vtrans<<<dim3(16, 64), blk, 0, stream>>>(qkvb, 3072, 2048, 1024, vt_self, 1024);
  k_attn<true><<<dim3(16, 64), blk, 0, stream>>>(
      qkvb, 3072, qkvb, 3072, 1024, 1024, vt_self, 1024, attnout, 1024);
  k_gemm<false, true, false, 1><<<dim3(8, 32), blk, 0, stream>>>(
      attnout, wt_aproj, aproj_b, x, nullptr, xres, nullptr, 4096, 1024, 1024);

  // 4. ln2(xres) ; q2 ; kv(enc) ; V-transpose ; cross-attn ; caproj + residual -> xres
  k_ln<<<dim3(4096), blk, 0, stream>>>(xres, ln2_g, ln2_b, lnout);
  k_gemm<false, false, true, 0><<<dim3(8, 32), blk, 0, stream>>>(
      lnout, wt_ca, ca_b, nullptr, nullptr, nullptr, q2b, 4096, 1024, 1024);
  k_gemm<false, false, true, 0><<<dim3(16, 9), blk, 0, stream>>>(
      encbf, wt_ca + (size_t)1024 * 1024, ca_b + 1024, nullptr, nullptr, nullptr, kvb,
      1028, 2048, 1024);
  k_vtrans<<<dim3(5, 64), blk, 0, stream>>>(kvb, 2048, 1024, 257, vt_cross, 320);
  k_attn<false><<<dim3(16, 64), blk, 0, stream>>>(
      q2b, 1024, kvb, 2048, 0, 257, vt_cross, 320, caout, 257);
  k_gemm<false, true, false, 1><<<dim3(8, 32), blk, 0, stream>>>(
      caout, wt_caproj, caproj_b, xres, nullptr, xres, nullptr, 4096, 1024, 1024);

  // 5. ln3(xres) ; fc+gelu ; mproj -> h (f32 + bf16)
  k_ln<<<dim3(4096), blk, 0, stream>>>(xres, ln3_g, ln3_b, lnout);
  k_gemm<true, false, true, 0><<<dim3(32, 32), blk, 0, stream>>>(
      lnout, wt_fc, fc_b, nullptr, nullptr, nullptr, fcout, 4096, 4096, 1024);
  k_gemm<false, true, true, 0><<<dim3(8, 32), blk, 0, stream>>>(
      fcout, wt_mproj, mproj_b, nullptr, nullptr, hf, hbf, 4096, 1024, 4096);

  // 6. adapter: down+gelu ; up + up_b + h + xres -> out
  k_gemm<true, false, true, 0><<<dim3(2, 32), blk, 0, stream>>>(
      hbf, wt_down, down_b, nullptr, nullptr, nullptr, dmid, 4096, 256, 1024);
  k_gemm<false, true, false, 2><<<dim3(8, 32), blk, 0, stream>>>(
      dmid, wt_up, up_b, hf, xres, out, nullptr, 4096, 1024, 256);
}